// Round 1
// 573.746 us; speedup vs baseline: 1.0059x; 1.0059x over previous
//
#include <hip/hip_runtime.h>

#define B_DIM 1024
#define NT 128
#define NY 128
#define C_DIM 512
#define EOS 1

// ---------------- DPP helpers (gfx9 lineage: row_shr / row_bcast / wave_shr) --------
// update_dpp: lanes whose DPP source is invalid (or masked out by row_mask) receive
// `oldv` -> we pass the scan identity there, which replaces the `if (lane >= s)` /
// `lane == 0` guards of the shfl version exactly.
template <int CTRL, int RM>
__device__ __forceinline__ float dpp_mov_f(float src, float oldv) {
    return __int_as_float(__builtin_amdgcn_update_dpp(
        __float_as_int(oldv), __float_as_int(src), CTRL, RM, 0xf, false));
}

// shift the whole wave right by 1 lane (lane 0 gets oldv)
__device__ __forceinline__ float wave_shr1_f(float src, float oldv) {
    return dpp_mov_f<0x138, 0xf>(src, oldv);
}

// one stage of the affine-pair scan: (A,D) <- (A + Ap*D, D*Dp), identity (0,1)
template <int CTRL, int RM>
__device__ __forceinline__ void scan_stage(float& A, float& D) {
    const float Ap = dpp_mov_f<CTRL, RM>(A, 0.0f);
    const float Dp = dpp_mov_f<CTRL, RM>(D, 1.0f);
    A = fmaf(Ap, D, A);
    D = D * Dp;
}

// full 64-lane inclusive affine scan: 4 intra-row stages + 2 row-broadcast stages
__device__ __forceinline__ void affine_scan64(float& A, float& D) {
    scan_stage<0x111, 0xf>(A, D);   // row_shr:1
    scan_stage<0x112, 0xf>(A, D);   // row_shr:2
    scan_stage<0x114, 0xf>(A, D);   // row_shr:4
    scan_stage<0x118, 0xf>(A, D);   // row_shr:8
    scan_stage<0x142, 0xa>(A, D);   // row_bcast:15 -> rows 1,3
    scan_stage<0x143, 0xc>(A, D);   // row_bcast:31 -> rows 2,3
}

// 64-lane inclusive multiply scan (for the row0 cumprod)
__device__ __forceinline__ float mul_scan64(float P) {
    P *= dpp_mov_f<0x111, 0xf>(P, 1.0f);
    P *= dpp_mov_f<0x112, 0xf>(P, 1.0f);
    P *= dpp_mov_f<0x114, 0xf>(P, 1.0f);
    P *= dpp_mov_f<0x118, 0xf>(P, 1.0f);
    P *= dpp_mov_f<0x142, 0xa>(P, 1.0f);
    P *= dpp_mov_f<0x143, 0xc>(P, 1.0f);
    return P;
}

// ---------------- Kernel 1: LDS-staged gather ----------------
// One wave per (b, j). The wave streams its 2KB pred row + 2KB I row with fully
// coalesced dwordx4 loads into LDS, then does the random 128-way gather from LDS
// (random over 32 banks ~= 2-way conflicts, free). All global traffic is now
// contiguous streams -> BW-bound instead of scatter-issue-bound.
__global__ __launch_bounds__(256) void gather_lds(
    const float* __restrict__ pred,
    const float* __restrict__ I,
    const int*   __restrict__ target,
    float*       __restrict__ Gp,   // [B][NY][NT]
    float*       __restrict__ Gi)   // [B][NY][NT]
{
    __shared__ float lp[4][C_DIM];
    __shared__ float li[4][C_DIM];
    __shared__ int   tg[NT];

    const int w    = threadIdx.x >> 6;
    const int lane = threadIdx.x & 63;
    const int wid  = blockIdx.x * 4 + w;   // = b*NY + j ; 4 consecutive j, same b
    const int b = wid >> 7;
    const int j = wid & (NY - 1);

    if (threadIdx.x < NT) tg[threadIdx.x] = target[(size_t)b * NT + threadIdx.x];

    const size_t rbase = ((size_t)b * NY + j) * C_DIM;
    const float4* pr4 = (const float4*)(pred + rbase);
    const float4* ii4 = (const float4*)(I + rbase);
    const float4 p0 = pr4[lane];
    const float4 p1 = pr4[64 + lane];
    const float4 q0 = ii4[lane];
    const float4 q1 = ii4[64 + lane];
    ((float4*)lp[w])[lane]      = p0;
    ((float4*)lp[w])[64 + lane] = p1;
    ((float4*)li[w])[lane]      = q0;
    ((float4*)li[w])[64 + lane] = q1;
    __syncthreads();

    const int tA = tg[lane];
    const int tB = tg[64 + lane];

    const size_t gbase = ((size_t)b * NY + j) * NT;
    Gp[gbase + lane]      = lp[w][tA];
    Gp[gbase + 64 + lane] = lp[w][tB];
    Gi[gbase + lane]      = li[w][tA];
    Gi[gbase + 64 + lane] = li[w][tB];
}

// ---------------- Kernel 2: per-batch affine scan (DPP cross-lane) ----------------
__global__ __launch_bounds__(64) void scan_kernel(
    const float* __restrict__ R,
    const int*   __restrict__ target,
    const float* __restrict__ Gp,
    const float* __restrict__ Gi,
    float*       __restrict__ out)
{
    const int b    = blockIdx.x;
    const int lane = threadIdx.x;
    const int j0   = 2 * lane;
    const int j1   = 2 * lane + 1;

    __shared__ int tg[NT];
    tg[j0] = target[(size_t)b * NT + j0];
    tg[j1] = target[(size_t)b * NT + j1];
    __syncthreads();

    const float* Rb = R + (size_t)b * NY * 3;
    const float R0j0 = Rb[j0 * 3 + 0];
    const float R1j0 = Rb[j0 * 3 + 1];
    const float R2j0 = Rb[j0 * 3 + 2];
    const float R0j1 = Rb[j1 * 3 + 0];
    const float R1j1 = Rb[j1 * 3 + 1];
    const float R2j1 = Rb[j1 * 3 + 2];
    const float R2m1 = wave_shr1_f(R2j1, 1.0f);   // R2[j0-1] (lane 0 value unused)

    // row0 = cumprod([1, pD0[1..127]])
    const int tgt0 = tg[0];
    const float e0 = (lane == 0) ? 1.0f : ((tgt0 == EOS) ? 1.0f : R2j0);
    const float e1 = (tgt0 == EOS) ? 1.0f : R2j1;
    float P = mul_scan64(e0 * e1);
    const float Pm1 = wave_shr1_f(P, 1.0f);       // lane 0 -> 1.0
    float row0v = Pm1 * e0;
    float row1v = P;

    const size_t gbase = (size_t)b * NY * NT;
    const float* gp0 = Gp + gbase + (size_t)j0 * NT;
    const float* gp1 = Gp + gbase + (size_t)j1 * NT;
    const float* gi0 = Gi + gbase + (size_t)j0 * NT;
    const float* gi1 = Gi + gbase + (size_t)j1 * NT;

    auto step = [&](float p0, float p1, float q0, float q1, int tgt_next) {
        const float pC0 = R0j0 * p0;
        const float pC1 = R0j1 * p1;
        const float pI0 = R1j0 * q0;
        const float pI1 = (lane == 63) ? q1 : R1j1 * q1;   // p_I[...,127] = I_T
        const float m1    = row1v * pC1;
        const float mprev = wave_shr1_f(m1, 0.0f);          // lane 0 -> 0
        const float a0 = fmaf(row0v, pI0, mprev);
        const float a1 = row0v * pC0 + row1v * pI1;
        const bool  eosn = (tgt_next == EOS);
        const float d0 = (lane == 0 || eosn) ? 1.0f : R2m1;
        const float d1 = eosn ? 1.0f : R2j0;
        float A = fmaf(d1, a0, a1);
        float D = d1 * d0;
        affine_scan64(A, D);
        const float Xm1 = wave_shr1_f(A, 0.0f);             // lane 0 -> 0
        row0v = fmaf(d0, Xm1, a0);
        row1v = A;
    };

    float4 cP0 = *(const float4*)(gp0);
    float4 cP1 = *(const float4*)(gp1);
    float4 cQ0 = *(const float4*)(gi0);
    float4 cQ1 = *(const float4*)(gi1);

    for (int tb = 0; tb < 124; tb += 4) {
        const float4 nP0 = *(const float4*)(gp0 + tb + 4);
        const float4 nP1 = *(const float4*)(gp1 + tb + 4);
        const float4 nQ0 = *(const float4*)(gi0 + tb + 4);
        const float4 nQ1 = *(const float4*)(gi1 + tb + 4);
        step(cP0.x, cP1.x, cQ0.x, cQ1.x, tg[tb + 1]);
        step(cP0.y, cP1.y, cQ0.y, cQ1.y, tg[tb + 2]);
        step(cP0.z, cP1.z, cQ0.z, cQ1.z, tg[tb + 3]);
        step(cP0.w, cP1.w, cQ0.w, cQ1.w, tg[tb + 4]);
        cP0 = nP0; cP1 = nP1; cQ0 = nQ0; cQ1 = nQ1;
    }
    // t = 124, 125, 126
    step(cP0.x, cP1.x, cQ0.x, cQ1.x, tg[125]);
    step(cP0.y, cP1.y, cQ0.y, cQ1.y, tg[126]);
    step(cP0.z, cP1.z, cQ0.z, cQ1.z, tg[127]);

    if (lane == 63) out[b] = row1v;
}

// ---------------- Fallback (round-1 kernel) if ws too small ----------------
__global__ __launch_bounds__(64) void eploss_fallback(
    const float* __restrict__ pred,
    const float* __restrict__ R,
    const float* __restrict__ I,
    const int*   __restrict__ target,
    float*       __restrict__ out)
{
    const int b    = blockIdx.x;
    const int lane = threadIdx.x;
    const int j0   = 2 * lane;
    const int j1   = 2 * lane + 1;

    __shared__ int tg[NT];
    tg[j0] = target[(size_t)b * NT + j0];
    tg[j1] = target[(size_t)b * NT + j1];
    __syncthreads();

    const float* Rb = R + (size_t)b * NY * 3;
    const float R0j0 = Rb[j0 * 3 + 0];
    const float R1j0 = Rb[j0 * 3 + 1];
    const float R2j0 = Rb[j0 * 3 + 2];
    const float R0j1 = Rb[j1 * 3 + 0];
    const float R1j1 = Rb[j1 * 3 + 1];
    const float R2j1 = Rb[j1 * 3 + 2];
    const float R2m1 = __shfl_up(R2j1, 1);

    const int tgt0 = tg[0];
    const float e0 = (lane == 0) ? 1.0f : ((tgt0 == EOS) ? 1.0f : R2j0);
    const float e1 = (tgt0 == EOS) ? 1.0f : R2j1;
    float P = e0 * e1;
    #pragma unroll
    for (int s = 1; s < 64; s <<= 1) {
        float Pp = __shfl_up(P, s);
        if (lane >= s) P *= Pp;
    }
    float Pm1 = __shfl_up(P, 1);
    if (lane == 0) Pm1 = 1.0f;
    float row0v = Pm1 * e0;
    float row1v = P;

    const size_t baseP = (size_t)b * NY * C_DIM;
    const float* pr0 = pred + baseP + (size_t)j0 * C_DIM;
    const float* pr1 = pred + baseP + (size_t)j1 * C_DIM;
    const float* Ii0 = I    + baseP + (size_t)j0 * C_DIM;
    const float* Ii1 = I    + baseP + (size_t)j1 * C_DIM;

    int tgt = tg[0];
    float p0 = pr0[tgt], p1 = pr1[tgt];
    float q0 = Ii0[tgt], q1 = Ii1[tgt];

    for (int t = 0; t < NT - 1; ++t) {
        const int tgt_next = tg[t + 1];
        float np0 = 0.f, np1 = 0.f, nq0 = 0.f, nq1 = 0.f;
        if (t + 1 < NT - 1) {
            np0 = pr0[tgt_next]; np1 = pr1[tgt_next];
            nq0 = Ii0[tgt_next]; nq1 = Ii1[tgt_next];
        }
        const float pC0 = R0j0 * p0;
        const float pC1 = R0j1 * p1;
        const float pI0 = R1j0 * q0;
        const float pI1 = (lane == 63) ? q1 : R1j1 * q1;
        const float m1 = row1v * pC1;
        const float mprev = __shfl_up(m1, 1);
        const float a0 = row0v * pI0 + ((lane == 0) ? 0.0f : mprev);
        const float a1 = row0v * pC0 + row1v * pI1;
        const bool eosn = (tgt_next == EOS);
        const float d0 = (lane == 0 || eosn) ? 1.0f : R2m1;
        const float d1 = eosn ? 1.0f : R2j0;
        float A = a1 + d1 * a0;
        float D = d1 * d0;
        #pragma unroll
        for (int s = 1; s < 64; s <<= 1) {
            float Ap = __shfl_up(A, s);
            float Dp = __shfl_up(D, s);
            if (lane >= s) { A = A + Ap * D; D = D * Dp; }
        }
        const float Xm1 = __shfl_up(A, 1);
        row0v = a0 + ((lane == 0) ? 0.0f : d0 * Xm1);
        row1v = A;
        p0 = np0; p1 = np1; q0 = nq0; q1 = nq1;
    }

    if (lane == 63) out[b] = row1v;
}

extern "C" void kernel_launch(void* const* d_in, const int* in_sizes, int n_in,
                              void* d_out, int out_size, void* d_ws, size_t ws_size,
                              hipStream_t stream) {
    const float* pred   = (const float*)d_in[0];
    const float* R      = (const float*)d_in[1];
    const float* I      = (const float*)d_in[2];
    const int*   target = (const int*)d_in[3];
    float* out = (float*)d_out;

    const size_t need = 2ull * B_DIM * NY * NT * sizeof(float);  // 134 MB
    if (ws_size >= need) {
        float* Gp = (float*)d_ws;
        float* Gi = Gp + (size_t)B_DIM * NY * NT;
        gather_lds<<<dim3(B_DIM * NY / 4), dim3(256), 0, stream>>>(pred, I, target, Gp, Gi);
        scan_kernel<<<dim3(B_DIM), dim3(64), 0, stream>>>(R, target, Gp, Gi, out);
    } else {
        eploss_fallback<<<dim3(B_DIM), dim3(64), 0, stream>>>(pred, R, I, target, out);
    }
}